// Round 11
// baseline (58.566 us; speedup 1.0000x reference)
//
#include <hip/hip_runtime.h>

// Sliding-window attention, window=127 (+-63), B=4 L=4096 NH=16 H=64, fp32 in/out.
// Round-11: two-phase LDS (K then V in the SAME 32KB) -> 4 blocks/CU.
//  - Phase A: stage K only; QK^T+softmax for all 5 tiles; P kept packed in regs
//    (5 tiles x 2 f16x8 = 40 VGPR, dataflow-forced -- compiler can't sink it).
//  - Phase B: V overwrites K's LDS; PV for all 5 tiles (O^T orientation, R9).
//  - 256 thr = 4 waves, one wave per 32-query tile, NO key-split -> no partial
//    exchange epilogue; dinv lane-local; direct float4 stores (R9, write-combining
//    verified clean 65.5MB).
//  - Q not staged (single consumer) -> direct strided prologue loads (R5-proven).
//  - LDS 32KB -> 4 blocks/CU (vs 2): more independent blocks to hide phase latency.
//  - FROZEN RULE (R3/R5): no register prefetch pinned across MFMA. V loads sit
//    after barrier b2 in program order; barriers fence hoisting.

typedef _Float16 f16;
typedef _Float16 f16x2  __attribute__((ext_vector_type(2)));
typedef _Float16 f16x4  __attribute__((ext_vector_type(4)));
typedef _Float16 f16x8  __attribute__((ext_vector_type(8)));
typedef float    f32x16 __attribute__((ext_vector_type(16)));
typedef int      int4v  __attribute__((ext_vector_type(4)));

constexpr int NB = 4, L = 4096, NH = 16, H = 64;
constexpr int CQ = 128, NC = L / CQ, KW = 256, WR = 63;
constexpr int RS = NH * H;        // seq-row stride in floats
constexpr int LDS_BYTES = 32768;  // K phase-A / V phase-B share this

#define DEV static __device__ __forceinline__

DEV int iclamp(int x, int lo, int hi) { return x < lo ? lo : (x > hi ? hi : x); }

DEV float fexp2(float x) {
#if __has_builtin(__builtin_amdgcn_exp2f)
    return __builtin_amdgcn_exp2f(x);
#else
    return exp2f(x);
#endif
}

DEV int packh2(float a, float b) {
    f16x2 p; p.x = (f16)a; p.y = (f16)b;   // RNE casts
    return __builtin_bit_cast(int, p);
}

// K: byte offset in row-major [256][64] f16 tile (128B rows), bank-conflict swizzle
DEV int kaddr(int r, int colb) {
    return r * 128 + (colb ^ ((r & 7) << 4));
}

// V: byte offset of (row h, key byte kb) in transposed [64][512B] layout, swizzled
DEV int vaddr(int h, int kb) {
    return (h * 512 + kb) ^ ((((h & 7) ^ ((h >> 3) & 7))) << 4);
}

// After call: a = [a_lo | b_lo], b = [a_hi | b_hi]. HW-verified (R7+).
DEV void swap_halves(int& a, int& b) {
    asm volatile("v_permlane32_swap_b32 %0, %1" : "+v"(a), "+v"(b));
}

__global__ __launch_bounds__(256, 4)
void wattn_kernel(const float* __restrict__ q_, const float* __restrict__ k_,
                  const float* __restrict__ v_, float* __restrict__ o_)
{
    __shared__ alignas(16) char smem[LDS_BYTES];

    // XCD-aware swizzle: 2048 blocks, 8 XCDs, 2048%8==0 -> bijective
    const int bid = (int)blockIdx.x;
    const int wid = (bid & 7) * ((NB * NH * NC) / 8) + (bid >> 3);
    const int c = wid & (NC - 1);
    const int n = (wid >> 5) & (NH - 1);
    const int b = wid >> 9;

    const int t    = (int)threadIdx.x;
    const int lane = t & 63;
    const int w    = t >> 6;        // wave 0..3 = query tile
    const int lq   = lane & 31;
    const int hi   = lane >> 5;

    const int kg0 = c * CQ - WR;                       // global seq row of window key j=0
    const size_t bn = ((size_t)b * L * NH + n) * H;    // element offset of (b,0,n,0)
    const float qs = 0.125f * 1.44269504088896f;       // h^-0.5 * log2(e)

    // staging thread->element mapping: 16 threads per 256B source row
    const int h4 = (t & 15) << 2;    // float col 0,4,..,60
    const int cb = h4 << 1;          // f16 byte col
    const int ru = t >> 4;           // 0..15

    // ---- Q prologue: direct strided loads -> scaled f16 fragments (one-time) ----
    const int iq = w * 32 + lq;
    const float* qrow = q_ + bn + (size_t)(c * CQ + iq) * RS + hi * 8;
    f16x8 qf[4];
    #pragma unroll
    for (int tq = 0; tq < 4; ++tq) {
        float4 a  = *(const float4*)(qrow + tq * 16);
        float4 b2 = *(const float4*)(qrow + tq * 16 + 4);
        qf[tq] = (f16x8){(f16)(a.x * qs),  (f16)(a.y * qs),  (f16)(a.z * qs),  (f16)(a.w * qs),
                         (f16)(b2.x * qs), (f16)(b2.y * qs), (f16)(b2.z * qs), (f16)(b2.w * qs)};
    }

    // ---- phase A stage: K rows 0..255 (edge-clamped; masked in softmax) ----
    #pragma unroll
    for (int p = 0; p < 16; ++p) {
        int r  = ru + p * 16;
        int kr = iclamp(kg0 + r, 0, L - 1);
        float4 x = *(const float4*)(k_ + bn + (size_t)kr * RS + h4);
        *(f16x4*)(smem + kaddr(r, cb)) = (f16x4){(f16)x.x, (f16)x.y, (f16)x.z, (f16)x.w};
    }

    // window mask bounds: allowed local keys j with j-iq in [0,126] and kg0+j in [0,L)
    const int jlo = (c == 0) ? WR : 0;
    const int jhi = (KW < L - kg0) ? KW : (L - kg0);
    const int lo  = (iq > jlo) ? iq : jlo;
    const int hb  = (iq + 126 < jhi - 1) ? (iq + 126) : (jhi - 1);
    const unsigned span = (unsigned)(hb - lo);

    float dsum = 0.f;
    f16x8 pa[5][2];   // packed P fragments, held across phases (dataflow-forced VGPRs)

    __syncthreads();   // b1: K staged

    // ================= phase A: QK^T + softmax for all 5 tiles =================
    #pragma unroll
    for (int i = 0; i < 5; ++i) {
        const int kt = w + i;
        f16x8 kf[4];
        #pragma unroll
        for (int tq = 0; tq < 4; ++tq)
            kf[tq] = *(const f16x8*)(smem + kaddr(kt * 32 + lq, 32 * tq + 16 * hi));

        f32x16 s;
        #pragma unroll
        for (int r = 0; r < 16; ++r) s[r] = 0.f;
        #pragma unroll
        for (int tq = 0; tq < 4; ++tq)
            s = __builtin_amdgcn_mfma_f32_32x32x16_f16(kf[tq], qf[tq], s, 0, 0, 0);

        const int jb = kt * 32 + 4 * hi;
        float pe[16];
        #pragma unroll
        for (int r = 0; r < 16; ++r) {
            int j = jb + (r & 3) + ((r >> 2) << 3);      // D-row -> local key index
            float e = fexp2(s[r]);
            e = ((unsigned)(j - lo) <= span) ? e : 0.f;
            dsum += e;
            pe[r] = e;
        }
        int d0 = packh2(pe[0],  pe[1]),  d1 = packh2(pe[2],  pe[3]);
        int d2 = packh2(pe[4],  pe[5]),  d3 = packh2(pe[6],  pe[7]);
        int d4 = packh2(pe[8],  pe[9]),  d5 = packh2(pe[10], pe[11]);
        int d6 = packh2(pe[12], pe[13]), d7 = packh2(pe[14], pe[15]);
        swap_halves(d0, d2); swap_halves(d1, d3);
        swap_halves(d4, d6); swap_halves(d5, d7);
        pa[i][0] = __builtin_bit_cast(f16x8, (int4v){d0, d1, d2, d3});   // keys kt*32 + 0..15
        pa[i][1] = __builtin_bit_cast(f16x8, (int4v){d4, d5, d6, d7});   // keys kt*32 + 16..31
    }

    __syncthreads();   // b2: all waves done reading K; LDS free for V

    // ---- phase B stage: V transposed [64h][256k] over old K region ----
    #pragma unroll
    for (int p = 0; p < 8; ++p) {
        int r0  = ru * 2 + p * 32;
        int kr0 = iclamp(kg0 + r0,     0, L - 1);
        int kr1 = iclamp(kg0 + r0 + 1, 0, L - 1);
        float4 v0 = *(const float4*)(v_ + bn + (size_t)kr0 * RS + h4);
        float4 v1 = *(const float4*)(v_ + bn + (size_t)kr1 * RS + h4);
        int kb = r0 * 2;
        *(f16x2*)(smem + vaddr(h4 + 0, kb)) = (f16x2){(f16)v0.x, (f16)v1.x};
        *(f16x2*)(smem + vaddr(h4 + 1, kb)) = (f16x2){(f16)v0.y, (f16)v1.y};
        *(f16x2*)(smem + vaddr(h4 + 2, kb)) = (f16x2){(f16)v0.z, (f16)v1.z};
        *(f16x2*)(smem + vaddr(h4 + 3, kb)) = (f16x2){(f16)v0.w, (f16)v1.w};
    }

    f32x16 o0, o1;   // O^T fragments: lane holds row q=lq, h = (r&3)+8(r>>2)+4hi (+32 for o1)
    #pragma unroll
    for (int r = 0; r < 16; ++r) { o0[r] = 0.f; o1[r] = 0.f; }

    __syncthreads();   // b3: V staged

    // ================= phase B: PV for all 5 tiles =================
    #pragma unroll
    for (int i = 0; i < 5; ++i) {
        const int kt = w + i;
        const int kb = kt * 64 + hi * 16;
        f16x8 vb00 = *(const f16x8*)(smem + vaddr(lq,      kb));
        f16x8 vb01 = *(const f16x8*)(smem + vaddr(lq,      kb + 32));
        f16x8 vb10 = *(const f16x8*)(smem + vaddr(32 + lq, kb));
        f16x8 vb11 = *(const f16x8*)(smem + vaddr(32 + lq, kb + 32));
        o0 = __builtin_amdgcn_mfma_f32_32x32x16_f16(vb00, pa[i][0], o0, 0, 0, 0);
        o0 = __builtin_amdgcn_mfma_f32_32x32x16_f16(vb01, pa[i][1], o0, 0, 0, 0);
        o1 = __builtin_amdgcn_mfma_f32_32x32x16_f16(vb10, pa[i][0], o1, 0, 0, 0);
        o1 = __builtin_amdgcn_mfma_f32_32x32x16_f16(vb11, pa[i][1], o1, 0, 0, 0);
    }

    // ---- epilogue: dinv lane-local (q = lq), direct float4 stores (R9-verified) ----
    float dtot = dsum + __shfl_xor(dsum, 32, 64);
    float dinv = 1.0f / dtot;
    const size_t ob = ((size_t)b * L + (size_t)c * CQ) * RS + (size_t)n * H;
    float* orow = o_ + ob + (size_t)iq * RS;
    #pragma unroll
    for (int m = 0; m < 4; ++m) {
        int h0 = 8 * m + 4 * hi;
        float4 v0, v1;
        v0.x = o0[4 * m + 0] * dinv;  v0.y = o0[4 * m + 1] * dinv;
        v0.z = o0[4 * m + 2] * dinv;  v0.w = o0[4 * m + 3] * dinv;
        v1.x = o1[4 * m + 0] * dinv;  v1.y = o1[4 * m + 1] * dinv;
        v1.z = o1[4 * m + 2] * dinv;  v1.w = o1[4 * m + 3] * dinv;
        *(float4*)(orow + h0)      = v0;
        *(float4*)(orow + 32 + h0) = v1;
    }
}

extern "C" void kernel_launch(void* const* d_in, const int* in_sizes, int n_in,
                              void* d_out, int out_size, void* d_ws, size_t ws_size,
                              hipStream_t stream) {
    const float* q = (const float*)d_in[0];
    const float* k = (const float*)d_in[1];
    const float* v = (const float*)d_in[2];
    float* o = (float*)d_out;
    (void)in_sizes; (void)n_in; (void)out_size; (void)d_ws; (void)ws_size;
    wattn_kernel<<<dim3(NB * NH * NC), dim3(256), 0, stream>>>(q, k, v, o);
}